// Round 2
// baseline (2962.221 us; speedup 1.0000x reference)
//
#include <hip/hip_runtime.h>
#include <hip/hip_bf16.h>

typedef unsigned short u16;

// Problem constants
#define BATCH 4
#define TSEQ  2048
#define HEADS 16
#define DK    64
#define EMB   1024            // HEADS*DK
#define MROWS (BATCH*TSEQ)    // 8192
#define NQKV  (3*EMB)         // 3072

__device__ __forceinline__ float bf2f(u16 u) {
    union { unsigned int i; float f; } v;
    v.i = ((unsigned int)u) << 16;
    return v.f;
}
__device__ __forceinline__ u16 f2bf(float f) {
    union { float f; unsigned int i; } v;
    v.f = f;
    unsigned int x = v.i;
    unsigned int r = (x + 0x7FFFu + ((x >> 16) & 1u)) >> 16;  // RNE
    return (u16)r;
}

// ---------------------------------------------------------------------------
// GEMM1: qkv = x @ W_qkv + b_qkv (all fp32 in), scattered into
// Q/K/V [3][B][H][T][DK] bf16 workspace.
// M=8192, N=3072, K=1024. 64x64 tile, BK=16, 256 threads, 4x4 per thread.
// ---------------------------------------------------------------------------
__global__ __launch_bounds__(256) void gemm_qkv(const float* __restrict__ X,
                                                const float* __restrict__ W,
                                                const float* __restrict__ bias,
                                                u16* __restrict__ qkv_ws) {
    const int K = EMB, N = NQKV;
    __shared__ float As[64][17];
    __shared__ float Bs[16][65];
    const int tid = threadIdx.x;
    const int tx = tid & 15, ty = tid >> 4;
    const int m0 = blockIdx.y * 64, n0 = blockIdx.x * 64;
    float acc[4][4] = {};

    for (int k0 = 0; k0 < K; k0 += 16) {
        // A tile 64x16 (1024 elems)
        for (int e = tid; e < 64 * 16; e += 256) {
            int r = e >> 4, c = e & 15;
            As[r][c] = X[(size_t)(m0 + r) * K + k0 + c];
        }
        // B tile 16x64 (1024 elems)
        for (int e = tid; e < 16 * 64; e += 256) {
            int r = e >> 6, c = e & 63;
            Bs[r][c] = W[(size_t)(k0 + r) * N + n0 + c];
        }
        __syncthreads();
#pragma unroll
        for (int kk = 0; kk < 16; kk++) {
            float a[4], b[4];
#pragma unroll
            for (int i = 0; i < 4; i++) a[i] = As[ty * 4 + i][kk];
#pragma unroll
            for (int j = 0; j < 4; j++) b[j] = Bs[kk][tx * 4 + j];
#pragma unroll
            for (int i = 0; i < 4; i++)
#pragma unroll
                for (int j = 0; j < 4; j++) acc[i][j] += a[i] * b[j];
        }
        __syncthreads();
    }

    // scatter with bias: n -> which (q/k/v), head, dim; m -> (b, t)
#pragma unroll
    for (int i = 0; i < 4; i++) {
        int m = m0 + ty * 4 + i;
        int b = m >> 11, t = m & 2047;
#pragma unroll
        for (int j = 0; j < 4; j++) {
            int n = n0 + tx * 4 + j;
            float v = acc[i][j] + bias[n];
            int which = n >> 10, rem = n & 1023;
            int h = rem >> 6, d = rem & 63;
            size_t off = (size_t)which * (BATCH * HEADS * TSEQ * DK) +
                         ((((size_t)b * HEADS + h) * TSEQ + t) * DK + d);
            qkv_ws[off] = f2bf(v);
        }
    }
}

// ---------------------------------------------------------------------------
// Flash-style causal attention. Grid: (T/64, B*H). Block 256 = 16x16 threads.
// Q/K/V in [B][H][T][DK] bf16; output [B][T][H][DK] bf16 (== GEMM2's row-major A).
// ---------------------------------------------------------------------------
__global__ __launch_bounds__(256) void attn(const u16* __restrict__ Qg,
                                            const u16* __restrict__ Kg,
                                            const u16* __restrict__ Vg,
                                            u16* __restrict__ Og) {
    __shared__ u16 Qs[64][DK + 2];
    __shared__ u16 Ks[64][DK + 2];
    __shared__ u16 Vs[64][DK + 2];
    __shared__ float S[64][65];
    __shared__ float mrow[64], lrow[64], arow[64];

    const int tid = threadIdx.x;
    const int tx = tid & 15, ty = tid >> 4;
    const int qt = blockIdx.x;
    const int bh = blockIdx.y;
    const size_t base = (size_t)bh * TSEQ * DK;
    const int r0 = ty * 4, c0 = tx * 4;
    const float scale = 0.125f;  // 1/sqrt(64)

    // load Q tile (64 x 64)
    for (int e = tid; e < 64 * DK; e += 256) {
        int r = e >> 6, c = e & 63;
        Qs[r][c] = Qg[base + (size_t)(qt * 64 + r) * DK + c];
    }
    if (tid < 64) { mrow[tid] = -1e30f; lrow[tid] = 0.f; }

    float O[4][4] = {};

    for (int kt = 0; kt <= qt; kt++) {
        __syncthreads();  // protect Ks/Vs/S reuse (and Q/stats init on first iter)
        for (int e = tid; e < 64 * DK; e += 256) {
            int r = e >> 6, c = e & 63;
            Ks[r][c] = Kg[base + (size_t)(kt * 64 + r) * DK + c];
            Vs[r][c] = Vg[base + (size_t)(kt * 64 + r) * DK + c];
        }
        __syncthreads();

        // S tile = Q . K^T (4x4 per thread over d=0..63)
        float s[4][4] = {};
#pragma unroll 8
        for (int d = 0; d < DK; d++) {
            float a[4], b[4];
#pragma unroll
            for (int i = 0; i < 4; i++) a[i] = bf2f(Qs[r0 + i][d]);
#pragma unroll
            for (int j = 0; j < 4; j++) b[j] = bf2f(Ks[c0 + j][d]);
#pragma unroll
            for (int i = 0; i < 4; i++)
#pragma unroll
                for (int j = 0; j < 4; j++) s[i][j] += a[i] * b[j];
        }
        // causal mask + scale -> LDS
#pragma unroll
        for (int i = 0; i < 4; i++) {
            int q = qt * 64 + r0 + i;
#pragma unroll
            for (int j = 0; j < 4; j++) {
                int k = kt * 64 + c0 + j;
                S[r0 + i][c0 + j] = (k <= q) ? s[i][j] * scale : -1e30f;
            }
        }
        __syncthreads();

        // online-softmax row pass (one thread per row; wave 0 only)
        if (tid < 64) {
            int r = tid;
            float m_old = mrow[r];
            float m_new = m_old;
            for (int c = 0; c < 64; c++) m_new = fmaxf(m_new, S[r][c]);
            float alpha = __expf(m_old - m_new);
            float sum = 0.f;
            for (int c = 0; c < 64; c++) {
                float p = __expf(S[r][c] - m_new);
                S[r][c] = p;
                sum += p;
            }
            mrow[r] = m_new;
            lrow[r] = lrow[r] * alpha + sum;
            arow[r] = alpha;
        }
        __syncthreads();

        // O = O*alpha + P @ V
        float al[4];
#pragma unroll
        for (int i = 0; i < 4; i++) al[i] = arow[r0 + i];
        float pv[4][4] = {};
#pragma unroll 8
        for (int kk = 0; kk < 64; kk++) {
            float p[4], v[4];
#pragma unroll
            for (int i = 0; i < 4; i++) p[i] = S[r0 + i][kk];
#pragma unroll
            for (int j = 0; j < 4; j++) v[j] = bf2f(Vs[kk][c0 + j]);
#pragma unroll
            for (int i = 0; i < 4; i++)
#pragma unroll
                for (int j = 0; j < 4; j++) pv[i][j] += p[i] * v[j];
        }
#pragma unroll
        for (int i = 0; i < 4; i++)
#pragma unroll
            for (int j = 0; j < 4; j++) O[i][j] = O[i][j] * al[i] + pv[i][j];
    }
    __syncthreads();

    // normalize + store to [B][T][H][DK]
    const int b = bh >> 4, h = bh & 15;
#pragma unroll
    for (int i = 0; i < 4; i++) {
        int q = qt * 64 + r0 + i;
        float inv = 1.f / lrow[r0 + i];
#pragma unroll
        for (int j = 0; j < 4; j++) {
            Og[(((size_t)b * TSEQ + q) * HEADS + h) * DK + c0 + j] = f2bf(O[i][j] * inv);
        }
    }
}

// ---------------------------------------------------------------------------
// GEMM2: out = attn_out @ W_o + b_o. M=8192, N=1024, K=1024.
// A is bf16 workspace [8192,1024]; W_o/b_o fp32; out fp32.
// ---------------------------------------------------------------------------
__global__ __launch_bounds__(256) void gemm_out(const u16* __restrict__ A,
                                                const float* __restrict__ W,
                                                const float* __restrict__ bias,
                                                float* __restrict__ out) {
    const int K = EMB, N = EMB;
    __shared__ float As[64][17];
    __shared__ float Bs[16][65];
    const int tid = threadIdx.x;
    const int tx = tid & 15, ty = tid >> 4;
    const int m0 = blockIdx.y * 64, n0 = blockIdx.x * 64;
    float acc[4][4] = {};

    for (int k0 = 0; k0 < K; k0 += 16) {
        for (int e = tid; e < 64 * 16; e += 256) {
            int r = e >> 4, c = e & 15;
            As[r][c] = bf2f(A[(size_t)(m0 + r) * K + k0 + c]);
        }
        for (int e = tid; e < 16 * 64; e += 256) {
            int r = e >> 6, c = e & 63;
            Bs[r][c] = W[(size_t)(k0 + r) * N + n0 + c];
        }
        __syncthreads();
#pragma unroll
        for (int kk = 0; kk < 16; kk++) {
            float a[4], b[4];
#pragma unroll
            for (int i = 0; i < 4; i++) a[i] = As[ty * 4 + i][kk];
#pragma unroll
            for (int j = 0; j < 4; j++) b[j] = Bs[kk][tx * 4 + j];
#pragma unroll
            for (int i = 0; i < 4; i++)
#pragma unroll
                for (int j = 0; j < 4; j++) acc[i][j] += a[i] * b[j];
        }
        __syncthreads();
    }

#pragma unroll
    for (int i = 0; i < 4; i++) {
        int m = m0 + ty * 4 + i;
#pragma unroll
        for (int j = 0; j < 4; j++) {
            int n = n0 + tx * 4 + j;
            out[(size_t)m * N + n] = acc[i][j] + bias[n];
        }
    }
}

// ---------------------------------------------------------------------------
extern "C" void kernel_launch(void* const* d_in, const int* in_sizes, int n_in,
                              void* d_out, int out_size, void* d_ws, size_t ws_size,
                              hipStream_t stream) {
    const float* x    = (const float*)d_in[0];  // [4,2048,1024] fp32
    const float* Wqkv = (const float*)d_in[1];  // [1024,3072]
    const float* bqkv = (const float*)d_in[2];  // [3072]
    const float* Wo   = (const float*)d_in[3];  // [1024,1024]
    const float* bo   = (const float*)d_in[4];  // [1024]
    float* out = (float*)d_out;                 // [4,2048,1024] fp32

    const size_t elems = (size_t)MROWS * EMB;  // 8388608
    u16* qkv_ws  = (u16*)d_ws;                 // Q,K,V: 3*elems bf16
    u16* attn_ws = qkv_ws + 3 * elems;         // [B,T,H,DK] bf16

    // 1) QKV projection, scattered to [B,H,T,DK]
    gemm_qkv<<<dim3(NQKV / 64, MROWS / 64), 256, 0, stream>>>(x, Wqkv, bqkv, qkv_ws);
    // 2) causal flash attention -> [B,T,H,DK] (= row-major [8192,1024])
    attn<<<dim3(TSEQ / 64, BATCH * HEADS), 256, 0, stream>>>(
        qkv_ws, qkv_ws + elems, qkv_ws + 2 * elems, attn_ws);
    // 3) output projection
    gemm_out<<<dim3(EMB / 64, MROWS / 64), 256, 0, stream>>>(attn_ws, Wo, bo, out);
}

// Round 4
// 449.823 us; speedup vs baseline: 6.5853x; 6.5853x over previous
//
#include <hip/hip_runtime.h>
#include <hip/hip_bf16.h>
#include <math.h>

typedef unsigned short u16;
typedef __attribute__((ext_vector_type(8))) short bf16x8;
typedef __attribute__((ext_vector_type(4))) float f32x4;

#define BATCH 4
#define TSEQ  2048
#define HEADS 16
#define DK    64
#define EMB   1024
#define MROWS 8192            // B*T
#define NQKV  3072
#define PHT   ((size_t)MROWS * EMB)   // 8388608 elems per Q/K/V plane

__device__ __forceinline__ u16 f2bf(float f) {
    union { float f; unsigned int i; } v;
    v.f = f;
    unsigned int x = v.i;
    return (u16)((x + 0x7FFFu + ((x >> 16) & 1u)) >> 16);  // RNE
}

// async 16B global->LDS (dest = wave-uniform base + lane*16)
__device__ __forceinline__ void gl2lds16(const u16* g, u16* l) {
    __builtin_amdgcn_global_load_lds(
        (const __attribute__((address_space(1))) unsigned int*)g,
        (__attribute__((address_space(3))) unsigned int*)l, 16, 0, 0);
}

// ---------------------------------------------------------------------------
// prep: fp32 -> bf16 convert (X), and fp32 [K][N] -> bf16 [N][K] transpose (W)
// ---------------------------------------------------------------------------
__global__ __launch_bounds__(256) void convert_x(const float* __restrict__ X,
                                                 u16* __restrict__ Xb) {
    int i = (blockIdx.x * 256 + threadIdx.x) * 4;
    float4 v = *(const float4*)&X[i];
    ushort4 o;
    o.x = f2bf(v.x); o.y = f2bf(v.y); o.z = f2bf(v.z); o.w = f2bf(v.w);
    *(ushort4*)&Xb[i] = o;
}

__global__ __launch_bounds__(256) void transpose_w(const float* __restrict__ W,
                                                   u16* __restrict__ Wt,
                                                   int K, int N) {
    __shared__ float tile[32][33];
    const int tx = threadIdx.x & 31, ty = threadIdx.x >> 5;  // 32 x 8
    const int bx = blockIdx.x, by = blockIdx.y;
#pragma unroll
    for (int s = 0; s < 4; s++)
        tile[ty + 8 * s][tx] = W[(size_t)(by * 32 + ty + 8 * s) * N + bx * 32 + tx];
    __syncthreads();
#pragma unroll
    for (int s = 0; s < 4; s++)
        Wt[(size_t)(bx * 32 + ty + 8 * s) * K + by * 32 + tx] = f2bf(tile[tx][ty + 8 * s]);
}

// ---------------------------------------------------------------------------
// MFMA GEMM core: acc[128x128 tile] += A[128xK] * Bt[128xK]^T ; BK=32,
// 4 waves, each wave 64x64 (4x4 MFMA tiles of 16x16x32 bf16).
// LDS staging via global_load_lds(16B), XOR-swizzled chunks.
// ---------------------------------------------------------------------------
template <int KDIM>
__device__ __forceinline__ void gemm_core(const u16* __restrict__ A,
                                          const u16* __restrict__ Bt,
                                          u16* As, u16* Bs,
                                          int m0, int n0, int wm, int wn,
                                          int tid, int lo, int quad,
                                          f32x4 (&acc)[4][4]) {
    for (int k0 = 0; k0 < KDIM; k0 += 32) {
        __syncthreads();
#pragma unroll
        for (int c = 0; c < 2; c++) {
            int chunk = c * 256 + tid;
            int row = chunk >> 2, p = chunk & 3;
            int pg = p ^ ((row >> 1) & 3);
            gl2lds16(A + (size_t)(m0 + row) * KDIM + k0 + pg * 8, As + chunk * 8);
            gl2lds16(Bt + (size_t)(n0 + row) * KDIM + k0 + pg * 8, Bs + chunk * 8);
        }
        __syncthreads();
        bf16x8 af[4], bw[4];
#pragma unroll
        for (int i = 0; i < 4; i++) {
            int r = wm + i * 16 + lo;
            int pp = quad ^ ((r >> 1) & 3);
            af[i] = *(const bf16x8*)&As[r * 32 + pp * 8];
        }
#pragma unroll
        for (int j = 0; j < 4; j++) {
            int r = wn + j * 16 + lo;
            int pp = quad ^ ((r >> 1) & 3);
            bw[j] = *(const bf16x8*)&Bs[r * 32 + pp * 8];
        }
#pragma unroll
        for (int i = 0; i < 4; i++)
#pragma unroll
            for (int j = 0; j < 4; j++)
                acc[i][j] = __builtin_amdgcn_mfma_f32_16x16x32_bf16(
                    af[i], bw[j], acc[i][j], 0, 0, 0);
    }
}

// GEMM1: qkv = Xb @ Wqkv_t^T + b, scattered to [3][B*H][T][DK] bf16
__global__ __launch_bounds__(256) void gemm1_mfma(const u16* __restrict__ A,
                                                  const u16* __restrict__ Bt,
                                                  const float* __restrict__ bias,
                                                  u16* __restrict__ qkv) {
    __shared__ u16 As[128 * 32];
    __shared__ u16 Bs[128 * 32];
    const int tid = threadIdx.x;
    const int lane = tid & 63, wv = tid >> 6;
    const int lo = lane & 15, quad = lane >> 4;
    const int m0 = blockIdx.y * 128, n0 = blockIdx.x * 128;
    const int wm = (wv >> 1) * 64, wn = (wv & 1) * 64;
    f32x4 acc[4][4] = {};

    gemm_core<1024>(A, Bt, As, Bs, m0, n0, wm, wn, tid, lo, quad, acc);

#pragma unroll
    for (int i = 0; i < 4; i++) {
#pragma unroll
        for (int r = 0; r < 4; r++) {
            int m = m0 + wm + i * 16 + quad * 4 + r;
            int b = m >> 11, t = m & 2047;
#pragma unroll
            for (int j = 0; j < 4; j++) {
                int n = n0 + wn + j * 16 + lo;
                float v = acc[i][j][r] + bias[n];
                int which = n >> 10, rem = n & 1023;
                int h = rem >> 6, d = rem & 63;
                qkv[(size_t)which * PHT +
                    (((size_t)(b * HEADS + h) * TSEQ + t) * DK + d)] = f2bf(v);
            }
        }
    }
}

// GEMM2: out = AO @ Wo_t^T + b (fp32 out)
__global__ __launch_bounds__(256) void gemm2_mfma(const u16* __restrict__ A,
                                                  const u16* __restrict__ Bt,
                                                  const float* __restrict__ bias,
                                                  float* __restrict__ out) {
    __shared__ u16 As[128 * 32];
    __shared__ u16 Bs[128 * 32];
    const int tid = threadIdx.x;
    const int lane = tid & 63, wv = tid >> 6;
    const int lo = lane & 15, quad = lane >> 4;
    const int m0 = blockIdx.y * 128, n0 = blockIdx.x * 128;
    const int wm = (wv >> 1) * 64, wn = (wv & 1) * 64;
    f32x4 acc[4][4] = {};

    gemm_core<1024>(A, Bt, As, Bs, m0, n0, wm, wn, tid, lo, quad, acc);

#pragma unroll
    for (int i = 0; i < 4; i++) {
#pragma unroll
        for (int r = 0; r < 4; r++) {
            int m = m0 + wm + i * 16 + quad * 4 + r;
#pragma unroll
            for (int j = 0; j < 4; j++) {
                int n = n0 + wn + j * 16 + lo;
                out[(size_t)m * EMB + n] = acc[i][j][r] + bias[n];
            }
        }
    }
}

// ---------------------------------------------------------------------------
// MFMA flash attention. Grid (T/128, B*H), 256 threads (4 waves).
// Wave w owns q-rows [w*32, w*32+32). K-tile = 64 keys.
// Q/K/V: [B*H][T][64] bf16.  Out: [B][T][H][64] bf16.
// ---------------------------------------------------------------------------
__global__ __launch_bounds__(256) void attn_mfma(const u16* __restrict__ Qg,
                                                 const u16* __restrict__ Kg,
                                                 const u16* __restrict__ Vg,
                                                 u16* __restrict__ AO) {
    __shared__ u16 Qs[128 * 64];      // swizzled
    __shared__ u16 Ks[64 * 64];       // swizzled
    __shared__ u16 Vt[64 * 64];       // V^T [dk][key], swizzled
    __shared__ u16 Ps[4][32 * 64];    // per-wave P, swizzled

    const int tid = threadIdx.x;
    const int lane = tid & 63, wv = tid >> 6;
    const int lo = lane & 15, quad = lane >> 4;
    const int qt = blockIdx.x, bh = blockIdx.y;
    const int q0 = qt * 128;
    const size_t base = (size_t)bh * TSEQ * DK;
    const float scale = 0.125f;  // 1/sqrt(64)

    // stage Q tile (128x64), swizzled 16B chunks
#pragma unroll
    for (int c = 0; c < 4; c++) {
        int chunk = c * 256 + tid;
        int row = chunk >> 3, p = chunk & 7;
        int pg = p ^ (row & 7);
        gl2lds16(Qg + base + (size_t)(q0 + row) * DK + pg * 8, Qs + chunk * 8);
    }

    f32x4 O[2][4] = {};
    float mrow[2][4], lrow[2][4];
#pragma unroll
    for (int i = 0; i < 2; i++)
#pragma unroll
        for (int r = 0; r < 4; r++) { mrow[i][r] = -INFINITY; lrow[i][r] = 0.f; }

    const int nkt = (qt + 1) * 2;
    for (int kt = 0; kt < nkt; kt++) {
        __syncthreads();  // protect K/Vt vs previous iteration's reads
        // stage K tile (64x64)
#pragma unroll
        for (int c = 0; c < 2; c++) {
            int chunk = c * 256 + tid;
            int row = chunk >> 3, p = chunk & 7;
            int pg = p ^ (row & 7);
            gl2lds16(Kg + base + (size_t)(kt * 64 + row) * DK + pg * 8, Ks + chunk * 8);
        }
        // stage V transposed: Vt[dk][key]; wave w covers dk chunks, lane = key
#pragma unroll
        for (int g = 0; g < 2; g++) {
            int c0 = g * 32 + wv * 8;
            bf16x8 vv = *(const bf16x8*)&Vg[base + (size_t)(kt * 64 + lane) * DK + c0];
#pragma unroll
            for (int q = 0; q < 8; q++) {
                int cc = c0 + q, rr = lane;
                Vt[cc * 64 + (((rr >> 3) ^ (cc & 7)) << 3) + (rr & 7)] = (u16)vv[q];
            }
        }
        __syncthreads();

        // S = Q K^T  (per wave: 2 row-tiles x 4 key-tiles, K-dim 64 = 2 MFMAs)
        f32x4 s[2][4] = {};
#pragma unroll
        for (int h = 0; h < 2; h++) {
            bf16x8 aq[2], bk[4];
#pragma unroll
            for (int i = 0; i < 2; i++) {
                int row = wv * 32 + i * 16 + lo;
                int pp = (h * 4 + quad) ^ (row & 7);
                aq[i] = *(const bf16x8*)&Qs[row * 64 + pp * 8];
            }
#pragma unroll
            for (int j = 0; j < 4; j++) {
                int row = j * 16 + lo;
                int pp = (h * 4 + quad) ^ (row & 7);
                bk[j] = *(const bf16x8*)&Ks[row * 64 + pp * 8];
            }
#pragma unroll
            for (int i = 0; i < 2; i++)
#pragma unroll
                for (int j = 0; j < 4; j++)
                    s[i][j] = __builtin_amdgcn_mfma_f32_16x16x32_bf16(aq[i], bk[j], s[i][j], 0, 0, 0);
        }

        // online softmax (rows live on (quad, reg) — no cross-lane for alpha)
#pragma unroll
        for (int i = 0; i < 2; i++) {
            float pv[4][4];  // [j][r]
#pragma unroll
            for (int j = 0; j < 4; j++) {
                int col = kt * 64 + j * 16 + lo;
#pragma unroll
                for (int r = 0; r < 4; r++) {
                    int row = q0 + wv * 32 + i * 16 + quad * 4 + r;
                    pv[j][r] = (col <= row) ? s[i][j][r] * scale : -INFINITY;
                }
            }
            float alpha[4];
#pragma unroll
            for (int r = 0; r < 4; r++) {
                float mt = fmaxf(fmaxf(pv[0][r], pv[1][r]), fmaxf(pv[2][r], pv[3][r]));
                mt = fmaxf(mt, __shfl_xor(mt, 1));
                mt = fmaxf(mt, __shfl_xor(mt, 2));
                mt = fmaxf(mt, __shfl_xor(mt, 4));
                mt = fmaxf(mt, __shfl_xor(mt, 8));
                float mnew = fmaxf(mrow[i][r], mt);
                alpha[r] = __expf(mrow[i][r] - mnew);
                mrow[i][r] = mnew;
                float rs = 0.f;
#pragma unroll
                for (int j = 0; j < 4; j++) {
                    float p = __expf(pv[j][r] - mnew);
                    pv[j][r] = p;
                    rs += p;
                }
                rs += __shfl_xor(rs, 1);
                rs += __shfl_xor(rs, 2);
                rs += __shfl_xor(rs, 4);
                rs += __shfl_xor(rs, 8);
                lrow[i][r] = lrow[i][r] * alpha[r] + rs;
            }
#pragma unroll
            for (int jn = 0; jn < 4; jn++)
#pragma unroll
                for (int r = 0; r < 4; r++) O[i][jn][r] *= alpha[r];
            // write P (C-layout -> A-layout via LDS), swizzled
#pragma unroll
            for (int j = 0; j < 4; j++)
#pragma unroll
                for (int r = 0; r < 4; r++) {
                    int row = i * 16 + quad * 4 + r;
                    int col = j * 16 + lo;
                    Ps[wv][row * 64 + (((col >> 3) ^ (row & 7)) << 3) + (col & 7)] =
                        f2bf(pv[j][r]);
                }
        }

        // O += P @ V   (K-dim 64 keys = 2 MFMAs)
#pragma unroll
        for (int h2 = 0; h2 < 2; h2++) {
            bf16x8 ap[2], bv[4];
#pragma unroll
            for (int i = 0; i < 2; i++) {
                int row = i * 16 + lo;
                int pp = (h2 * 4 + quad) ^ (row & 7);
                ap[i] = *(const bf16x8*)&Ps[wv][row * 64 + pp * 8];
            }
#pragma unroll
            for (int jn = 0; jn < 4; jn++) {
                int row = jn * 16 + lo;  // dk index
                int pp = (h2 * 4 + quad) ^ (row & 7);
                bv[jn] = *(const bf16x8*)&Vt[row * 64 + pp * 8];
            }
#pragma unroll
            for (int i = 0; i < 2; i++)
#pragma unroll
                for (int jn = 0; jn < 4; jn++)
                    O[i][jn] = __builtin_amdgcn_mfma_f32_16x16x32_bf16(ap[i], bv[jn], O[i][jn], 0, 0, 0);
        }
    }

    // epilogue: normalize, store [B][T][H][DK] bf16
    const int b = bh >> 4, h = bh & 15;
#pragma unroll
    for (int i = 0; i < 2; i++)
#pragma unroll
        for (int r = 0; r < 4; r++) {
            int qrow = q0 + wv * 32 + i * 16 + quad * 4 + r;
            float inv = 1.f / lrow[i][r];
#pragma unroll
            for (int jn = 0; jn < 4; jn++) {
                int d = jn * 16 + lo;
                AO[(((size_t)b * TSEQ + qrow) * HEADS + h) * DK + d] = f2bf(O[i][jn][r] * inv);
            }
        }
}

// ---------------------------------------------------------------------------
extern "C" void kernel_launch(void* const* d_in, const int* in_sizes, int n_in,
                              void* d_out, int out_size, void* d_ws, size_t ws_size,
                              hipStream_t stream) {
    const float* x    = (const float*)d_in[0];
    const float* Wqkv = (const float*)d_in[1];
    const float* bqkv = (const float*)d_in[2];
    const float* Wo   = (const float*)d_in[3];
    const float* bo   = (const float*)d_in[4];
    float* out = (float*)d_out;

    // workspace layout (u16 elems): [Xb 8.4M | Wt 3.1M | Wot 1M | QKV 25.2M]
    u16* Xb  = (u16*)d_ws;
    u16* Wt  = Xb + PHT;                    // [3072][1024]
    u16* Wot = Wt + (size_t)NQKV * EMB;     // [1024][1024]
    u16* qkv = Wot + (size_t)EMB * EMB;     // 3 planes of [B*H][T][64]
    u16* AO  = Xb;                          // overlay: Xb dead after gemm1

    convert_x<<<MROWS * EMB / 1024, 256, 0, stream>>>(x, Xb);
    transpose_w<<<dim3(NQKV / 32, EMB / 32), 256, 0, stream>>>(Wqkv, Wt, EMB, NQKV);
    transpose_w<<<dim3(EMB / 32, EMB / 32), 256, 0, stream>>>(Wo, Wot, EMB, EMB);

    gemm1_mfma<<<dim3(NQKV / 128, MROWS / 128), 256, 0, stream>>>(Xb, Wt, bqkv, qkv);
    attn_mfma<<<dim3(TSEQ / 128, BATCH * HEADS), 256, 0, stream>>>(
        qkv, qkv + PHT, qkv + 2 * PHT, AO);
    gemm2_mfma<<<dim3(EMB / 128, MROWS / 128), 256, 0, stream>>>(AO, Wot, bo, out);
}

// Round 5
// 330.695 us; speedup vs baseline: 8.9576x; 1.3602x over previous
//
#include <hip/hip_runtime.h>
#include <hip/hip_bf16.h>
#include <math.h>

typedef unsigned short u16;
typedef __attribute__((ext_vector_type(8))) short bf16x8;
typedef __attribute__((ext_vector_type(4))) float f32x4;

#define BATCH 4
#define TSEQ  2048
#define HEADS 16
#define DK    64
#define EMB   1024
#define MROWS 8192            // B*T
#define NQKV  3072
#define PHT   ((size_t)MROWS * EMB)   // 8388608 elems per Q/K/V plane

__device__ __forceinline__ u16 f2bf(float f) {
    union { float f; unsigned int i; } v;
    v.f = f;
    unsigned int x = v.i;
    return (u16)((x + 0x7FFFu + ((x >> 16) & 1u)) >> 16);  // RNE
}

// async 16B global->LDS (dest = wave-uniform base + lane*16)
__device__ __forceinline__ void gl2lds16(const u16* g, u16* l) {
    __builtin_amdgcn_global_load_lds(
        (const __attribute__((address_space(1))) unsigned int*)g,
        (__attribute__((address_space(3))) unsigned int*)l, 16, 0, 0);
}

// ---------------------------------------------------------------------------
// prep: fp32 -> bf16 convert (X), and fp32 [K][N] -> bf16 [N][K] transpose (W)
// ---------------------------------------------------------------------------
__global__ __launch_bounds__(256) void convert_x(const float* __restrict__ X,
                                                 u16* __restrict__ Xb) {
    int i = (blockIdx.x * 256 + threadIdx.x) * 4;
    float4 v = *(const float4*)&X[i];
    ushort4 o;
    o.x = f2bf(v.x); o.y = f2bf(v.y); o.z = f2bf(v.z); o.w = f2bf(v.w);
    *(ushort4*)&Xb[i] = o;
}

__global__ __launch_bounds__(256) void transpose_w(const float* __restrict__ W,
                                                   u16* __restrict__ Wt,
                                                   int K, int N) {
    __shared__ float tile[32][33];
    const int tx = threadIdx.x & 31, ty = threadIdx.x >> 5;  // 32 x 8
    const int bx = blockIdx.x, by = blockIdx.y;
#pragma unroll
    for (int s = 0; s < 4; s++)
        tile[ty + 8 * s][tx] = W[(size_t)(by * 32 + ty + 8 * s) * N + bx * 32 + tx];
    __syncthreads();
#pragma unroll
    for (int s = 0; s < 4; s++)
        Wt[(size_t)(bx * 32 + ty + 8 * s) * K + by * 32 + tx] = f2bf(tile[tx][ty + 8 * s]);
}

// ---------------------------------------------------------------------------
// MFMA GEMM core: acc[128x128 tile] += A[128xK] * Bt[128xK]^T ; BK=32,
// 4 waves, each wave 64x64 (4x4 MFMA tiles of 16x16x32 bf16).
// LDS staging via global_load_lds(16B), XOR-swizzled chunks.
// ---------------------------------------------------------------------------
template <int KDIM>
__device__ __forceinline__ void gemm_core(const u16* __restrict__ A,
                                          const u16* __restrict__ Bt,
                                          u16* As, u16* Bs,
                                          int m0, int n0, int wm, int wn,
                                          int tid, int lo, int quad,
                                          f32x4 (&acc)[4][4]) {
    for (int k0 = 0; k0 < KDIM; k0 += 32) {
        __syncthreads();
#pragma unroll
        for (int c = 0; c < 2; c++) {
            int chunk = c * 256 + tid;
            int row = chunk >> 2, p = chunk & 3;
            int pg = p ^ ((row >> 1) & 3);
            gl2lds16(A + (size_t)(m0 + row) * KDIM + k0 + pg * 8, As + chunk * 8);
            gl2lds16(Bt + (size_t)(n0 + row) * KDIM + k0 + pg * 8, Bs + chunk * 8);
        }
        __syncthreads();
        bf16x8 af[4], bw[4];
#pragma unroll
        for (int i = 0; i < 4; i++) {
            int r = wm + i * 16 + lo;
            int pp = quad ^ ((r >> 1) & 3);
            af[i] = *(const bf16x8*)&As[r * 32 + pp * 8];
        }
#pragma unroll
        for (int j = 0; j < 4; j++) {
            int r = wn + j * 16 + lo;
            int pp = quad ^ ((r >> 1) & 3);
            bw[j] = *(const bf16x8*)&Bs[r * 32 + pp * 8];
        }
#pragma unroll
        for (int i = 0; i < 4; i++)
#pragma unroll
            for (int j = 0; j < 4; j++)
                acc[i][j] = __builtin_amdgcn_mfma_f32_16x16x32_bf16(
                    af[i], bw[j], acc[i][j], 0, 0, 0);
    }
}

// GEMM1: qkv = Xb @ Wqkv_t^T + b.  Q,K scattered to [bh][t][d];
// V written TRANSPOSED to [bh][d][t] (ushort4-packed along t).
__global__ __launch_bounds__(256) void gemm1_mfma(const u16* __restrict__ A,
                                                  const u16* __restrict__ Bt,
                                                  const float* __restrict__ bias,
                                                  u16* __restrict__ qkv) {
    __shared__ u16 As[128 * 32];
    __shared__ u16 Bs[128 * 32];
    const int tid = threadIdx.x;
    const int lane = tid & 63, wv = tid >> 6;
    const int lo = lane & 15, quad = lane >> 4;
    const int m0 = blockIdx.y * 128, n0 = blockIdx.x * 128;
    const int wm = (wv >> 1) * 64, wn = (wv & 1) * 64;
    f32x4 acc[4][4] = {};

    gemm_core<1024>(A, Bt, As, Bs, m0, n0, wm, wn, tid, lo, quad, acc);

    const int whichw = (n0 + wn) >> 10;   // uniform per wave (V iff ==2)
    if (whichw == 2) {
        // V plane: [bh][d][t], pack 4 consecutive t (C-layout rows) per store
#pragma unroll
        for (int i = 0; i < 4; i++) {
            int mb = m0 + wm + i * 16 + quad * 4;
            int b = mb >> 11, t = mb & 2047;
#pragma unroll
            for (int j = 0; j < 4; j++) {
                int n = n0 + wn + j * 16 + lo;
                int rem = n & 1023;
                int h = rem >> 6, d = rem & 63;
                float bn = bias[n];
                ushort4 o;
                o.x = f2bf(acc[i][j][0] + bn);
                o.y = f2bf(acc[i][j][1] + bn);
                o.z = f2bf(acc[i][j][2] + bn);
                o.w = f2bf(acc[i][j][3] + bn);
                *(ushort4*)&qkv[2 * PHT +
                                (((size_t)(b * HEADS + h) * DK + d) * TSEQ + t)] = o;
            }
        }
    } else {
#pragma unroll
        for (int i = 0; i < 4; i++) {
#pragma unroll
            for (int r = 0; r < 4; r++) {
                int m = m0 + wm + i * 16 + quad * 4 + r;
                int b = m >> 11, t = m & 2047;
#pragma unroll
                for (int j = 0; j < 4; j++) {
                    int n = n0 + wn + j * 16 + lo;
                    float v = acc[i][j][r] + bias[n];
                    int rem = n & 1023;
                    int h = rem >> 6, d = rem & 63;
                    qkv[(size_t)whichw * PHT +
                        (((size_t)(b * HEADS + h) * TSEQ + t) * DK + d)] = f2bf(v);
                }
            }
        }
    }
}

// GEMM2: out = AO @ Wo_t^T + b (fp32 out)
__global__ __launch_bounds__(256) void gemm2_mfma(const u16* __restrict__ A,
                                                  const u16* __restrict__ Bt,
                                                  const float* __restrict__ bias,
                                                  float* __restrict__ out) {
    __shared__ u16 As[128 * 32];
    __shared__ u16 Bs[128 * 32];
    const int tid = threadIdx.x;
    const int lane = tid & 63, wv = tid >> 6;
    const int lo = lane & 15, quad = lane >> 4;
    const int m0 = blockIdx.y * 128, n0 = blockIdx.x * 128;
    const int wm = (wv >> 1) * 64, wn = (wv & 1) * 64;
    f32x4 acc[4][4] = {};

    gemm_core<1024>(A, Bt, As, Bs, m0, n0, wm, wn, tid, lo, quad, acc);

#pragma unroll
    for (int i = 0; i < 4; i++) {
#pragma unroll
        for (int r = 0; r < 4; r++) {
            int m = m0 + wm + i * 16 + quad * 4 + r;
#pragma unroll
            for (int j = 0; j < 4; j++) {
                int n = n0 + wn + j * 16 + lo;
                out[(size_t)m * EMB + n] = acc[i][j][r] + bias[n];
            }
        }
    }
}

// ---------------------------------------------------------------------------
// MFMA flash attention v2. Grid (8 pairs, B*H), 256 threads (4 waves).
// Block p handles q-tiles {p, 15-p} (128 rows each) -> exactly 17 k-iterations
// of 128 keys -> perfectly balanced, all 512 blocks resident (2/CU @ 80KB LDS).
// Q,K: [bh][t][d] bf16.  V: [bh][d][t] bf16 (pre-transposed by gemm1).
// Out: [B][T][H][64] bf16.
// ---------------------------------------------------------------------------
__global__ __launch_bounds__(256, 2) void attn_mfma(const u16* __restrict__ Qg,
                                                    const u16* __restrict__ Kg,
                                                    const u16* __restrict__ Vg,
                                                    u16* __restrict__ AO) {
    __shared__ u16 Qs[128 * 64];      // [qrow][d], 8 chunks/row, swizzle row&7
    __shared__ u16 Ks[128 * 64];      // [key][d],  8 chunks/row, swizzle row&7
    __shared__ u16 Vt[64 * 128];      // [d][key], 16 chunks/row, swizzle row&15
    __shared__ u16 Ps[4][32 * 128];   // per-wave P, 16 chunks/row, swizzle row&15

    const int tid = threadIdx.x;
    const int lane = tid & 63, wv = tid >> 6;
    const int lo = lane & 15, quad = lane >> 4;
    const int pair = blockIdx.x, bh = blockIdx.y;
    const size_t base = (size_t)bh * TSEQ * DK;   // Q/K and V plane stride equal
    const float scale2 = 0.18033688011112042f;    // (1/sqrt(64)) * log2(e)
    const int b = bh >> 4, h = bh & 15;

    for (int qi = 0; qi < 2; qi++) {
        const int qt = qi ? (15 - pair) : pair;
        const int q0 = qt * 128;

        __syncthreads();  // previous q-tile's Qs/Ks/Vt readers done
        // stage Q tile (128x64)
#pragma unroll
        for (int c = 0; c < 4; c++) {
            int chunk = c * 256 + tid;
            int row = chunk >> 3, p = chunk & 7;
            int pg = p ^ (row & 7);
            gl2lds16(Qg + base + (size_t)(q0 + row) * DK + pg * 8, Qs + chunk * 8);
        }

        f32x4 O[2][4] = {};
        float mrow[2][4], lrow[2][4];
#pragma unroll
        for (int i = 0; i < 2; i++)
#pragma unroll
            for (int r = 0; r < 4; r++) { mrow[i][r] = -INFINITY; lrow[i][r] = 0.f; }

        for (int kt = 0; kt <= qt; kt++) {
            __syncthreads();
            // stage K tile (128 keys x 64 d)
#pragma unroll
            for (int c = 0; c < 4; c++) {
                int chunk = c * 256 + tid;
                int row = chunk >> 3, p = chunk & 7;
                int pg = p ^ (row & 7);
                gl2lds16(Kg + base + (size_t)(kt * 128 + row) * DK + pg * 8,
                         Ks + chunk * 8);
            }
            // stage V^T tile (64 d x 128 keys) straight from [bh][d][t]
#pragma unroll
            for (int c = 0; c < 4; c++) {
                int chunk = c * 256 + tid;
                int row = chunk >> 4, p = chunk & 15;
                int pg = p ^ (row & 15);
                gl2lds16(Vg + base + (size_t)row * TSEQ + kt * 128 + pg * 8,
                         Vt + chunk * 8);
            }
            __syncthreads();

            // S = Q K^T : rows 32 (2 tiles), keys 128 (8 tiles), K-dim 64
            f32x4 s[2][8] = {};
#pragma unroll
            for (int hh = 0; hh < 2; hh++) {
                bf16x8 aq[2];
#pragma unroll
                for (int i = 0; i < 2; i++) {
                    int row = wv * 32 + i * 16 + lo;
                    int ch = (hh * 4 + quad) ^ (row & 7);
                    aq[i] = *(const bf16x8*)&Qs[row * 64 + ch * 8];
                }
#pragma unroll
                for (int j = 0; j < 8; j++) {
                    int row = j * 16 + lo;
                    int ch = (hh * 4 + quad) ^ (row & 7);
                    bf16x8 bk = *(const bf16x8*)&Ks[row * 64 + ch * 8];
                    s[0][j] = __builtin_amdgcn_mfma_f32_16x16x32_bf16(aq[0], bk, s[0][j], 0, 0, 0);
                    s[1][j] = __builtin_amdgcn_mfma_f32_16x16x32_bf16(aq[1], bk, s[1][j], 0, 0, 0);
                }
            }

            const bool diag = (kt == qt);
            // online softmax (exp2 domain) + P write
#pragma unroll
            for (int i = 0; i < 2; i++) {
#pragma unroll
                for (int j = 0; j < 8; j++) {
                    int cl = j * 16 + lo;
#pragma unroll
                    for (int r = 0; r < 4; r++) {
                        float v = s[i][j][r] * scale2;
                        if (diag) {
                            int rq = wv * 32 + i * 16 + quad * 4 + r;
                            v = (cl <= rq) ? v : -INFINITY;
                        }
                        s[i][j][r] = v;
                    }
                }
#pragma unroll
                for (int r = 0; r < 4; r++) {
                    float mt = s[i][0][r];
#pragma unroll
                    for (int j = 1; j < 8; j++) mt = fmaxf(mt, s[i][j][r]);
                    mt = fmaxf(mt, __shfl_xor(mt, 1));
                    mt = fmaxf(mt, __shfl_xor(mt, 2));
                    mt = fmaxf(mt, __shfl_xor(mt, 4));
                    mt = fmaxf(mt, __shfl_xor(mt, 8));
                    float mnew = fmaxf(mrow[i][r], mt);
                    float alpha = exp2f(mrow[i][r] - mnew);
                    mrow[i][r] = mnew;
                    float rs = 0.f;
#pragma unroll
                    for (int j = 0; j < 8; j++) {
                        float pv = exp2f(s[i][j][r] - mnew);
                        s[i][j][r] = pv;
                        rs += pv;
                    }
                    rs += __shfl_xor(rs, 1);
                    rs += __shfl_xor(rs, 2);
                    rs += __shfl_xor(rs, 4);
                    rs += __shfl_xor(rs, 8);
                    lrow[i][r] = lrow[i][r] * alpha + rs;
#pragma unroll
                    for (int jn = 0; jn < 4; jn++) O[i][jn][r] *= alpha;
                }
                // P: C-layout -> A-layout via per-wave LDS (swizzled)
#pragma unroll
                for (int j = 0; j < 8; j++) {
                    int cl = j * 16 + lo;
#pragma unroll
                    for (int r = 0; r < 4; r++) {
                        int rl = i * 16 + quad * 4 + r;
                        Ps[wv][rl * 128 + (((cl >> 3) ^ (rl & 15)) << 3) + (cl & 7)] =
                            f2bf(s[i][j][r]);
                    }
                }
            }

            // O += P @ V : K-dim 128 keys = 4 MFMA k-steps
#pragma unroll
            for (int h2 = 0; h2 < 4; h2++) {
                bf16x8 ap[2], bv[4];
#pragma unroll
                for (int i = 0; i < 2; i++) {
                    int rl = i * 16 + lo;
                    int ch = (h2 * 4 + quad) ^ lo;   // rl&15 == lo
                    ap[i] = *(const bf16x8*)&Ps[wv][rl * 128 + ch * 8];
                }
#pragma unroll
                for (int jn = 0; jn < 4; jn++) {
                    int dr = jn * 16 + lo;
                    int ch = (h2 * 4 + quad) ^ lo;   // dr&15 == lo
                    bv[jn] = *(const bf16x8*)&Vt[dr * 128 + ch * 8];
                }
#pragma unroll
                for (int i = 0; i < 2; i++)
#pragma unroll
                    for (int jn = 0; jn < 4; jn++)
                        O[i][jn] = __builtin_amdgcn_mfma_f32_16x16x32_bf16(
                            ap[i], bv[jn], O[i][jn], 0, 0, 0);
            }
        }

        // epilogue: normalize, store [B][T][H][DK] bf16
#pragma unroll
        for (int i = 0; i < 2; i++)
#pragma unroll
            for (int r = 0; r < 4; r++) {
                int qrow = q0 + wv * 32 + i * 16 + quad * 4 + r;
                float inv = 1.f / lrow[i][r];
#pragma unroll
                for (int jn = 0; jn < 4; jn++) {
                    int d = jn * 16 + lo;
                    AO[(((size_t)b * TSEQ + qrow) * HEADS + h) * DK + d] =
                        f2bf(O[i][jn][r] * inv);
                }
            }
    }
}

// ---------------------------------------------------------------------------
extern "C" void kernel_launch(void* const* d_in, const int* in_sizes, int n_in,
                              void* d_out, int out_size, void* d_ws, size_t ws_size,
                              hipStream_t stream) {
    const float* x    = (const float*)d_in[0];
    const float* Wqkv = (const float*)d_in[1];
    const float* bqkv = (const float*)d_in[2];
    const float* Wo   = (const float*)d_in[3];
    const float* bo   = (const float*)d_in[4];
    float* out = (float*)d_out;

    // workspace layout (u16 elems): [Xb 8.4M | Wt 3.1M | Wot 1M | QKV 25.2M]
    u16* Xb  = (u16*)d_ws;
    u16* Wt  = Xb + PHT;                    // [3072][1024]
    u16* Wot = Wt + (size_t)NQKV * EMB;     // [1024][1024]
    u16* qkv = Wot + (size_t)EMB * EMB;     // Q,K: [bh][t][d]; V: [bh][d][t]
    u16* AO  = Xb;                          // overlay: Xb dead after gemm1

    convert_x<<<MROWS * EMB / 1024, 256, 0, stream>>>(x, Xb);
    transpose_w<<<dim3(NQKV / 32, EMB / 32), 256, 0, stream>>>(Wqkv, Wt, EMB, NQKV);
    transpose_w<<<dim3(EMB / 32, EMB / 32), 256, 0, stream>>>(Wo, Wot, EMB, EMB);

    gemm1_mfma<<<dim3(NQKV / 128, MROWS / 128), 256, 0, stream>>>(Xb, Wt, bqkv, qkv);
    attn_mfma<<<dim3(8, BATCH * HEADS), 256, 0, stream>>>(
        qkv, qkv + PHT, qkv + 2 * PHT, AO);
    gemm2_mfma<<<dim3(EMB / 128, MROWS / 128), 256, 0, stream>>>(AO, Wot, bo, out);
}

// Round 6
// 257.046 us; speedup vs baseline: 11.5241x; 1.2865x over previous
//
#include <hip/hip_runtime.h>
#include <hip/hip_bf16.h>
#include <math.h>

typedef unsigned short u16;
typedef __attribute__((ext_vector_type(8))) short bf16x8;
typedef __attribute__((ext_vector_type(4))) float f32x4;

#define BATCH 4
#define TSEQ  2048
#define HEADS 16
#define DK    64
#define EMB   1024
#define MROWS 8192            // B*T
#define NQKV  3072
#define PHT   ((size_t)MROWS * EMB)   // 8388608 elems per Q/K/V plane

__device__ __forceinline__ u16 f2bf(float f) {
    union { float f; unsigned int i; } v;
    v.f = f;
    unsigned int x = v.i;
    return (u16)((x + 0x7FFFu + ((x >> 16) & 1u)) >> 16);  // RNE
}

// packed 2xfp32 -> 2xbf16 (RNE) in one u32
__device__ __forceinline__ unsigned int pk2bf(float a, float b) {
    float2 f2; f2.x = a; f2.y = b;
    union { __hip_bfloat162 h; unsigned int u; } cv;
    cv.h = __float22bfloat162_rn(f2);
    return cv.u;
}

// async 16B global->LDS (dest = wave-uniform base + lane*16)
__device__ __forceinline__ void gl2lds16(const u16* g, u16* l) {
    __builtin_amdgcn_global_load_lds(
        (const __attribute__((address_space(1))) unsigned int*)g,
        (__attribute__((address_space(3))) unsigned int*)l, 16, 0, 0);
}

// ---------------------------------------------------------------------------
// prep: fp32 -> bf16 convert (X), and fp32 [K][N] -> bf16 [N][K] transpose (W)
// ---------------------------------------------------------------------------
__global__ __launch_bounds__(256) void convert_x(const float* __restrict__ X,
                                                 u16* __restrict__ Xb) {
    int i = (blockIdx.x * 256 + threadIdx.x) * 4;
    float4 v = *(const float4*)&X[i];
    ushort4 o;
    o.x = f2bf(v.x); o.y = f2bf(v.y); o.z = f2bf(v.z); o.w = f2bf(v.w);
    *(ushort4*)&Xb[i] = o;
}

__global__ __launch_bounds__(256) void transpose_w(const float* __restrict__ W,
                                                   u16* __restrict__ Wt,
                                                   int K, int N) {
    __shared__ float tile[32][33];
    const int tx = threadIdx.x & 31, ty = threadIdx.x >> 5;  // 32 x 8
    const int bx = blockIdx.x, by = blockIdx.y;
#pragma unroll
    for (int s = 0; s < 4; s++)
        tile[ty + 8 * s][tx] = W[(size_t)(by * 32 + ty + 8 * s) * N + bx * 32 + tx];
    __syncthreads();
#pragma unroll
    for (int s = 0; s < 4; s++)
        Wt[(size_t)(bx * 32 + ty + 8 * s) * K + by * 32 + tx] = f2bf(tile[tx][ty + 8 * s]);
}

// ---------------------------------------------------------------------------
// MFMA GEMM core (m97 structure): BK=32, 4 waves, wave does 64x64.
// ---------------------------------------------------------------------------
template <int KDIM>
__device__ __forceinline__ void gemm_core(const u16* __restrict__ A,
                                          const u16* __restrict__ Bt,
                                          u16* As, u16* Bs,
                                          int m0, int n0, int wm, int wn,
                                          int tid, int lo, int quad,
                                          f32x4 (&acc)[4][4]) {
    for (int k0 = 0; k0 < KDIM; k0 += 32) {
        __syncthreads();
#pragma unroll
        for (int c = 0; c < 2; c++) {
            int chunk = c * 256 + tid;
            int row = chunk >> 2, p = chunk & 3;
            int pg = p ^ ((row >> 1) & 3);
            gl2lds16(A + (size_t)(m0 + row) * KDIM + k0 + pg * 8, As + chunk * 8);
            gl2lds16(Bt + (size_t)(n0 + row) * KDIM + k0 + pg * 8, Bs + chunk * 8);
        }
        __syncthreads();
        bf16x8 af[4], bw[4];
#pragma unroll
        for (int i = 0; i < 4; i++) {
            int r = wm + i * 16 + lo;
            int pp = quad ^ ((r >> 1) & 3);
            af[i] = *(const bf16x8*)&As[r * 32 + pp * 8];
        }
#pragma unroll
        for (int j = 0; j < 4; j++) {
            int r = wn + j * 16 + lo;
            int pp = quad ^ ((r >> 1) & 3);
            bw[j] = *(const bf16x8*)&Bs[r * 32 + pp * 8];
        }
#pragma unroll
        for (int i = 0; i < 4; i++)
#pragma unroll
            for (int j = 0; j < 4; j++)
                acc[i][j] = __builtin_amdgcn_mfma_f32_16x16x32_bf16(
                    af[i], bw[j], acc[i][j], 0, 0, 0);
    }
}

// GEMM1: qkv = Xb @ Wqkv_t^T + b.  Q scattered to [bh][t][d] PRE-SCALED by
// (1/sqrt(dk))*log2(e); K to [bh][t][d]; V TRANSPOSED to [bh][d][t].
__global__ __launch_bounds__(256) void gemm1_mfma(const u16* __restrict__ A,
                                                  const u16* __restrict__ Bt,
                                                  const float* __restrict__ bias,
                                                  u16* __restrict__ qkv) {
    __shared__ u16 As[128 * 32];
    __shared__ u16 Bs[128 * 32];
    const int tid = threadIdx.x;
    const int lane = tid & 63, wv = tid >> 6;
    const int lo = lane & 15, quad = lane >> 4;
    const int m0 = blockIdx.y * 128, n0 = blockIdx.x * 128;
    const int wm = (wv >> 1) * 64, wn = (wv & 1) * 64;
    const float scale2 = 0.18033688011112042f;  // (1/8) * log2(e)
    f32x4 acc[4][4] = {};

    gemm_core<1024>(A, Bt, As, Bs, m0, n0, wm, wn, tid, lo, quad, acc);

    const int whichw = (n0 + wn) >> 10;   // uniform per wave (0=Q,1=K,2=V)
    if (whichw == 2) {
        // V plane: [bh][d][t], pack 4 consecutive t (C-layout rows) per store
#pragma unroll
        for (int i = 0; i < 4; i++) {
            int mb = m0 + wm + i * 16 + quad * 4;
            int b = mb >> 11, t = mb & 2047;
#pragma unroll
            for (int j = 0; j < 4; j++) {
                int n = n0 + wn + j * 16 + lo;
                int rem = n & 1023;
                int h = rem >> 6, d = rem & 63;
                float bn = bias[n];
                ushort4 o;
                o.x = f2bf(acc[i][j][0] + bn);
                o.y = f2bf(acc[i][j][1] + bn);
                o.z = f2bf(acc[i][j][2] + bn);
                o.w = f2bf(acc[i][j][3] + bn);
                *(ushort4*)&qkv[2 * PHT +
                                (((size_t)(b * HEADS + h) * DK + d) * TSEQ + t)] = o;
            }
        }
    } else {
        const float sc = (whichw == 0) ? scale2 : 1.0f;
#pragma unroll
        for (int i = 0; i < 4; i++) {
#pragma unroll
            for (int r = 0; r < 4; r++) {
                int m = m0 + wm + i * 16 + quad * 4 + r;
                int b = m >> 11, t = m & 2047;
#pragma unroll
                for (int j = 0; j < 4; j++) {
                    int n = n0 + wn + j * 16 + lo;
                    float v = (acc[i][j][r] + bias[n]) * sc;
                    int rem = n & 1023;
                    int h = rem >> 6, d = rem & 63;
                    qkv[(size_t)whichw * PHT +
                        (((size_t)(b * HEADS + h) * TSEQ + t) * DK + d)] = f2bf(v);
                }
            }
        }
    }
}

// GEMM2: out = AO @ Wo_t^T + b (fp32 out)
__global__ __launch_bounds__(256) void gemm2_mfma(const u16* __restrict__ A,
                                                  const u16* __restrict__ Bt,
                                                  const float* __restrict__ bias,
                                                  float* __restrict__ out) {
    __shared__ u16 As[128 * 32];
    __shared__ u16 Bs[128 * 32];
    const int tid = threadIdx.x;
    const int lane = tid & 63, wv = tid >> 6;
    const int lo = lane & 15, quad = lane >> 4;
    const int m0 = blockIdx.y * 128, n0 = blockIdx.x * 128;
    const int wm = (wv >> 1) * 64, wn = (wv & 1) * 64;
    f32x4 acc[4][4] = {};

    gemm_core<1024>(A, Bt, As, Bs, m0, n0, wm, wn, tid, lo, quad, acc);

#pragma unroll
    for (int i = 0; i < 4; i++) {
#pragma unroll
        for (int r = 0; r < 4; r++) {
            int m = m0 + wm + i * 16 + quad * 4 + r;
#pragma unroll
            for (int j = 0; j < 4; j++) {
                int n = n0 + wn + j * 16 + lo;
                out[(size_t)m * EMB + n] = acc[i][j][r] + bias[n];
            }
        }
    }
}

// ---------------------------------------------------------------------------
// MFMA flash attention v3 (no-max softmax). Grid (8 pairs, B*H), 256 threads.
// Block p does q-tiles {p, 15-p} -> exactly 17 k-iterations of 128 keys.
// S^T = K @ Q^T so P-LDS writes are packed b64; l via ones-fragment MFMA.
// Q (pre-scaled), K: [bh][t][d].  V: [bh][d][t].  Out: [B][T][H][64] bf16.
// LDS 48KB: Ks | Vt | R (Q staging overlaid with per-wave P).
// ---------------------------------------------------------------------------
__global__ __launch_bounds__(256, 2) void attn_mfma(const u16* __restrict__ Qg,
                                                    const u16* __restrict__ Kg,
                                                    const u16* __restrict__ Vg,
                                                    u16* __restrict__ AO) {
    __shared__ u16 pool[3 * 8192];
    u16* Ks = pool;            // [key 128][d 64], swizzle chunk^(row&7)
    u16* Vt = pool + 8192;     // [d 64][key 128], swizzle chunk^(row&15)
    u16* Rr = pool + 16384;    // Q staging (128x64) then per-wave P (32x64 each)

    const int tid = threadIdx.x;
    const int lane = tid & 63, wv = tid >> 6;
    const int lo = lane & 15, quad = lane >> 4;
    const int pair = blockIdx.x, bh = blockIdx.y;
    const size_t base = (size_t)bh * TSEQ * DK;
    const int b = bh >> 4, h = bh & 15;
    const bf16x8 onesf = {0x3F80, 0x3F80, 0x3F80, 0x3F80,
                          0x3F80, 0x3F80, 0x3F80, 0x3F80};

    for (int qi = 0; qi < 2; qi++) {
        const int qt = qi ? (15 - pair) : pair;
        const int q0 = qt * 128;

        __syncthreads();  // prior tile's Ps/Ks/Vt readers done
        // stage Q tile (128x64) into Rr
#pragma unroll
        for (int c = 0; c < 4; c++) {
            int chunk = c * 256 + tid;
            int row = chunk >> 3, p = chunk & 7;
            int pg = p ^ (row & 7);
            gl2lds16(Qg + base + (size_t)(q0 + row) * DK + pg * 8, Rr + chunk * 8);
        }
        __syncthreads();  // Q ready

        // hoist Q B-fragments (kt-invariant)
        bf16x8 bq[2][2];
#pragma unroll
        for (int i = 0; i < 2; i++)
#pragma unroll
            for (int hh = 0; hh < 2; hh++) {
                int row = wv * 32 + i * 16 + lo;
                int ch = (hh * 4 + quad) ^ (row & 7);
                bq[i][hh] = *(const bf16x8*)&Rr[row * 64 + ch * 8];
            }

        f32x4 O[2][5] = {};   // [i][0..3 = d-tiles, 4 = row-sum l]

        for (int kt = 0; kt <= qt; kt++) {
            __syncthreads();  // Ks/Vt readers done; also orders bq reads < Ps writes
            // stage K tile (128 keys x 64 d)
#pragma unroll
            for (int c = 0; c < 4; c++) {
                int chunk = c * 256 + tid;
                int row = chunk >> 3, p = chunk & 7;
                int pg = p ^ (row & 7);
                gl2lds16(Kg + base + (size_t)(kt * 128 + row) * DK + pg * 8,
                         Ks + chunk * 8);
            }
            // stage V^T tile (64 d x 128 keys)
#pragma unroll
            for (int c = 0; c < 4; c++) {
                int chunk = c * 256 + tid;
                int row = chunk >> 4, p = chunk & 15;
                int pg = p ^ (row & 15);
                gl2lds16(Vg + base + (size_t)row * TSEQ + kt * 128 + pg * 8,
                         Vt + chunk * 8);
            }
            __syncthreads();

            const bool diag = (kt == qt);
            u16* Ps = Rr + wv * 2048;   // per-wave 32 rows x 64 keys (half-tile)

#pragma unroll
            for (int jh = 0; jh < 2; jh++) {
                // S^T = K @ Q^T for 64-key half: st[j2][i]
                f32x4 st[4][2] = {};
#pragma unroll
                for (int hh = 0; hh < 2; hh++) {
#pragma unroll
                    for (int j2 = 0; j2 < 4; j2++) {
                        int row = (jh * 4 + j2) * 16 + lo;
                        int ch = (hh * 4 + quad) ^ (row & 7);
                        bf16x8 ak = *(const bf16x8*)&Ks[row * 64 + ch * 8];
                        st[j2][0] = __builtin_amdgcn_mfma_f32_16x16x32_bf16(
                            ak, bq[0][hh], st[j2][0], 0, 0, 0);
                        st[j2][1] = __builtin_amdgcn_mfma_f32_16x16x32_bf16(
                            ak, bq[1][hh], st[j2][1], 0, 0, 0);
                    }
                }
                // P = exp2(S^T) (no max), causal-mask on diagonal tile only,
                // packed b64 write to Ps[row=qrow][key]
#pragma unroll
                for (int j2 = 0; j2 < 4; j2++) {
#pragma unroll
                    for (int i = 0; i < 2; i++) {
                        float e[4];
#pragma unroll
                        for (int r = 0; r < 4; r++)
                            e[r] = __builtin_amdgcn_exp2f(st[j2][i][r]);
                        if (diag) {
                            int qr = q0 + wv * 32 + i * 16 + lo;
                            int kb = kt * 128 + (jh * 4 + j2) * 16 + quad * 4;
#pragma unroll
                            for (int r = 0; r < 4; r++)
                                if (kb + r > qr) e[r] = 0.f;
                        }
                        uint2 w;
                        w.x = pk2bf(e[0], e[1]);
                        w.y = pk2bf(e[2], e[3]);
                        int rowl = i * 16 + lo;
                        int chp = (2 * j2 + (quad >> 1)) ^ (lo & 7);
                        *(uint2*)&Ps[rowl * 64 + chp * 8 + (quad & 1) * 4] = w;
                    }
                }
                // O += P @ V for this 64-key half (2 MFMA k-steps)
#pragma unroll
                for (int hp = 0; hp < 2; hp++) {
                    bf16x8 ap[2], bv[4];
#pragma unroll
                    for (int i = 0; i < 2; i++) {
                        int rowl = i * 16 + lo;
                        int ch = (4 * hp + quad) ^ (lo & 7);
                        ap[i] = *(const bf16x8*)&Ps[rowl * 64 + ch * 8];
                    }
#pragma unroll
                    for (int jn = 0; jn < 4; jn++) {
                        int vrow = jn * 16 + lo;   // d index
                        int ch = (8 * jh + 4 * hp + quad) ^ (vrow & 15);
                        bv[jn] = *(const bf16x8*)&Vt[vrow * 128 + ch * 8];
                    }
#pragma unroll
                    for (int i = 0; i < 2; i++) {
#pragma unroll
                        for (int jn = 0; jn < 4; jn++)
                            O[i][jn] = __builtin_amdgcn_mfma_f32_16x16x32_bf16(
                                ap[i], bv[jn], O[i][jn], 0, 0, 0);
                        O[i][4] = __builtin_amdgcn_mfma_f32_16x16x32_bf16(
                            ap[i], onesf, O[i][4], 0, 0, 0);
                    }
                }
            }
        }

        // epilogue: normalize by l, store [B][T][H][DK] bf16
#pragma unroll
        for (int i = 0; i < 2; i++)
#pragma unroll
            for (int r = 0; r < 4; r++) {
                int qrow = q0 + wv * 32 + i * 16 + quad * 4 + r;
                float inv = 1.f / O[i][4][r];
#pragma unroll
                for (int jn = 0; jn < 4; jn++) {
                    int d = jn * 16 + lo;
                    AO[(((size_t)b * TSEQ + qrow) * HEADS + h) * DK + d] =
                        f2bf(O[i][jn][r] * inv);
                }
            }
    }
}

// ---------------------------------------------------------------------------
extern "C" void kernel_launch(void* const* d_in, const int* in_sizes, int n_in,
                              void* d_out, int out_size, void* d_ws, size_t ws_size,
                              hipStream_t stream) {
    const float* x    = (const float*)d_in[0];
    const float* Wqkv = (const float*)d_in[1];
    const float* bqkv = (const float*)d_in[2];
    const float* Wo   = (const float*)d_in[3];
    const float* bo   = (const float*)d_in[4];
    float* out = (float*)d_out;

    // workspace layout (u16 elems): [Xb 8.4M | Wt 3.1M | Wot 1M | QKV 25.2M]
    u16* Xb  = (u16*)d_ws;
    u16* Wt  = Xb + PHT;                    // [3072][1024]
    u16* Wot = Wt + (size_t)NQKV * EMB;     // [1024][1024]
    u16* qkv = Wot + (size_t)EMB * EMB;     // Q,K: [bh][t][d]; V: [bh][d][t]
    u16* AO  = Xb;                          // overlay: Xb dead after gemm1

    convert_x<<<MROWS * EMB / 1024, 256, 0, stream>>>(x, Xb);
    transpose_w<<<dim3(NQKV / 32, EMB / 32), 256, 0, stream>>>(Wqkv, Wt, EMB, NQKV);
    transpose_w<<<dim3(EMB / 32, EMB / 32), 256, 0, stream>>>(Wo, Wot, EMB, EMB);

    gemm1_mfma<<<dim3(NQKV / 128, MROWS / 128), 256, 0, stream>>>(Xb, Wt, bqkv, qkv);
    attn_mfma<<<dim3(8, BATCH * HEADS), 256, 0, stream>>>(
        qkv, qkv + PHT, qkv + 2 * PHT, AO);
    gemm2_mfma<<<dim3(EMB / 128, MROWS / 128), 256, 0, stream>>>(AO, Wot, bo, out);
}